// Round 1
// baseline (655.836 us; speedup 1.0000x reference)
//
#include <hip/hip_runtime.h>

#define D_IN   1024
#define D_OUTD 8192
#define ORDER  3
#define NCOL   2048
#define LOGD   13

// Persistent device-side tables (rewritten every kernel_launch call).
__device__ float2 g_tw[D_OUTD / 2];      // W_8192^k = exp(-2*pi*i*k/8192), k in [0,4096)
__device__ int    g_h[ORDER * D_IN];
__device__ float  g_w[ORDER * D_IN];

__global__ void tw_kernel() {
    int k = blockIdx.x * 256 + threadIdx.x;
    if (k < D_OUTD / 2) {
        double ang = -2.0 * 3.14159265358979323846 * (double)k / (double)D_OUTD;
        g_tw[k] = make_float2((float)cos(ang), (float)sin(ang));
    }
}

__global__ void extract_kernel(const float* __restrict__ hmaps) {
    int idx = blockIdx.x * 256 + threadIdx.x;       // < 25,165,824 fits int
    if (idx >= ORDER * D_OUTD * D_IN) return;
    float v = hmaps[idx];
    if (v != 0.0f) {
        int i   = idx % D_IN;
        int rem = idx / D_IN;
        int d   = rem % D_OUTD;
        int o   = rem / D_OUTD;
        g_h[o * D_IN + i] = d;
        g_w[o * D_IN + i] = v;
    }
}

// One workgroup per column n. 256 threads. 64KB LDS (one complex array of 8192).
// Forward: Gentleman-Sande DIF (natural in -> bit-reversed out).
// Product accumulated in registers (32 complex per thread).
// Inverse: Cooley-Tukey DIT (bit-reversed in -> natural out), conj twiddles, 1/N scale.
__launch_bounds__(256, 2)
__global__ void sketch_kernel(const float* __restrict__ x, float* __restrict__ outbuf,
                              int staged) {
    __shared__ float sre[D_OUTD];
    __shared__ float sim[D_OUTD];
    const int n   = blockIdx.x;
    const int tid = threadIdx.x;

    // Load this column of x into registers (reused for all 3 orders).
    float xr[4];
#pragma unroll
    for (int j = 0; j < 4; ++j) xr[j] = x[(tid + 256 * j) * NCOL + n];

    float Pre[32], Pim[32];

    for (int o = 0; o < ORDER; ++o) {
        // zero LDS
#pragma unroll
        for (int t = 0; t < 32; ++t) {
            sre[tid + 256 * t] = 0.0f;
            sim[tid + 256 * t] = 0.0f;
        }
        __syncthreads();
        // sparse scatter: count[o][d] += w[o][i] * x[i][n]
#pragma unroll
        for (int j = 0; j < 4; ++j) {
            int i = tid + 256 * j;
            int d = g_h[o * D_IN + i];
            atomicAdd(&sre[d], g_w[o * D_IN + i] * xr[j]);
        }
        __syncthreads();

        // forward DIF FFT (13 radix-2 stages)
        for (int lh = LOGD - 1; lh >= 0; --lh) {
            int half = 1 << lh;
#pragma unroll 4
            for (int t = 0; t < 16; ++t) {
                int b    = tid + 256 * t;              // butterfly id 0..4095
                int j    = b & (half - 1);
                int idx0 = ((b >> lh) << (lh + 1)) + j;
                int idx1 = idx0 + half;
                float ur = sre[idx0], ui = sim[idx0];
                float vr = sre[idx1], vi = sim[idx1];
                float2 w = g_tw[j << (12 - lh)];
                sre[idx0] = ur + vr;
                sim[idx0] = ui + vi;
                float br = ur - vr, bi = ui - vi;
                sre[idx1] = br * w.x - bi * w.y;
                sim[idx1] = br * w.y + bi * w.x;
            }
            __syncthreads();
        }

        // accumulate spectral product into registers (bit-reversed order is fine)
        if (o == 0) {
#pragma unroll
            for (int t = 0; t < 32; ++t) {
                int k = tid + 256 * t;
                Pre[t] = sre[k];
                Pim[t] = sim[k];
            }
        } else {
#pragma unroll
            for (int t = 0; t < 32; ++t) {
                int k  = tid + 256 * t;
                float ar = Pre[t], ai = Pim[t];
                float br = sre[k], bi = sim[k];
                Pre[t] = ar * br - ai * bi;
                Pim[t] = ar * bi + ai * br;
            }
        }
        __syncthreads();
    }

    // write product back to LDS
#pragma unroll
    for (int t = 0; t < 32; ++t) {
        int k = tid + 256 * t;
        sre[k] = Pre[t];
        sim[k] = Pim[t];
    }
    __syncthreads();

    // inverse DIT FFT (bit-reversed in -> natural out), twiddle = conj
    for (int lh = 0; lh < LOGD; ++lh) {
        int half = 1 << lh;
#pragma unroll 4
        for (int t = 0; t < 16; ++t) {
            int b    = tid + 256 * t;
            int j    = b & (half - 1);
            int idx0 = ((b >> lh) << (lh + 1)) + j;
            int idx1 = idx0 + half;
            float2 w = g_tw[j << (12 - lh)];       // use conj(w)
            float vr = sre[idx1], vi = sim[idx1];
            float tr = vr * w.x + vi * w.y;
            float ti = vi * w.x - vr * w.y;
            float ur = sre[idx0], ui = sim[idx0];
            sre[idx0] = ur + tr;
            sim[idx0] = ui + ti;
            sre[idx1] = ur - tr;
            sim[idx1] = ui - ti;
        }
        __syncthreads();
    }

    const float scale = 1.0f / (float)D_OUTD;
    if (staged) {
        // coalesced: staging buffer is [N][D_out]
#pragma unroll
        for (int t = 0; t < 32; ++t) {
            int d = tid + 256 * t;
            outbuf[n * D_OUTD + d] = sre[d] * scale;
        }
    } else {
        // fallback: strided direct write to [D_out][N]
#pragma unroll
        for (int t = 0; t < 32; ++t) {
            int d = tid + 256 * t;
            outbuf[d * NCOL + n] = sre[d] * scale;
        }
    }
}

// [N][D_out] -> [D_out][N], 32x32 tiles
__global__ void transpose_kernel(const float* __restrict__ in, float* __restrict__ out) {
    __shared__ float tile[32][33];
    int d0 = blockIdx.x * 32;
    int n0 = blockIdx.y * 32;
    int tx = threadIdx.x;   // 0..31
    int ty = threadIdx.y;   // 0..7
#pragma unroll
    for (int j = 0; j < 32; j += 8)
        tile[ty + j][tx] = in[(n0 + ty + j) * D_OUTD + d0 + tx];
    __syncthreads();
#pragma unroll
    for (int j = 0; j < 32; j += 8)
        out[(d0 + ty + j) * NCOL + n0 + tx] = tile[tx][ty + j];
}

extern "C" void kernel_launch(void* const* d_in, const int* in_sizes, int n_in,
                              void* d_out, int out_size, void* d_ws, size_t ws_size,
                              hipStream_t stream) {
    (void)in_sizes; (void)n_in; (void)out_size;
    const float* x     = (const float*)d_in[0];
    const float* hmaps = (const float*)d_in[1];
    float* out = (float*)d_out;

    tw_kernel<<<(D_OUTD / 2 + 255) / 256, 256, 0, stream>>>();
    extract_kernel<<<(ORDER * D_OUTD * D_IN + 255) / 256, 256, 0, stream>>>(hmaps);

    size_t need = (size_t)NCOL * D_OUTD * sizeof(float);
    if (ws_size >= need) {
        float* stag = (float*)d_ws;
        sketch_kernel<<<NCOL, 256, 0, stream>>>(x, stag, 1);
        transpose_kernel<<<dim3(D_OUTD / 32, NCOL / 32), dim3(32, 8), 0, stream>>>(stag, out);
    } else {
        sketch_kernel<<<NCOL, 256, 0, stream>>>(x, out, 0);
    }
}

// Round 2
// 526.870 us; speedup vs baseline: 1.2448x; 1.2448x over previous
//
#include <hip/hip_runtime.h>

#define D_IN   1024
#define D_OUTD 8192
#define ORDER  3
#define NCOL   2048

// Persistent device-side tables (rewritten every kernel_launch call).
__device__ float2 g_tw[D_OUTD / 2];      // W_8192^k, k in [0,4096)
__device__ int    g_h[ORDER * D_IN];
__device__ float  g_w[ORDER * D_IN];

__global__ void tw_kernel() {
    int k = blockIdx.x * 256 + threadIdx.x;
    if (k < D_OUTD / 2) {
        double ang = -2.0 * 3.14159265358979323846 * (double)k / (double)D_OUTD;
        g_tw[k] = make_float2((float)cos(ang), (float)sin(ang));
    }
}

__global__ void extract_kernel(const float* __restrict__ hmaps) {
    int idx = blockIdx.x * 256 + threadIdx.x;
    if (idx >= ORDER * D_OUTD * D_IN) return;
    float v = hmaps[idx];
    if (v != 0.0f) {
        int i   = idx % D_IN;
        int rem = idx / D_IN;
        int d   = rem % D_OUTD;
        int o   = rem / D_OUTD;
        g_h[o * D_IN + i] = d;
        g_w[o * D_IN + i] = v;
    }
}

// 512 threads per column n. 16 complex points per thread, register-resident FFT.
// Forward DIF: phase A (strides 4096..512, reg) -> LDS exchange -> phase B
// (256..32, reg) -> phase C (16..1, shfl_xor). Product in registers.
// Inverse DIT mirrors it. One LDS exchange per FFT instead of 13 stage round-trips.
__launch_bounds__(512, 4)
__global__ void sketch_kernel(const float* __restrict__ x, float* __restrict__ outbuf,
                              int staged) {
    __shared__ float bre[D_OUTD];
    __shared__ float bim[D_OUTD];
    const int n = blockIdx.x;
    const int t = threadIdx.x;
    const int s = t & 31;
    const int base = ((t >> 5) << 9) + s;   // 512*b + s

    const float xv0 = x[t * NCOL + n];
    const float xv1 = x[(t + 512) * NCOL + n];

    float Pre[16], Pim[16];
    float Xre[16], Xim[16];

    for (int o = 0; o < ORDER; ++o) {
        // ---- scatter count[o][.] into bre ----
#pragma unroll
        for (int j = 0; j < 16; ++j) bre[t + 512 * j] = 0.0f;
        __syncthreads();
        {
            const int   h0 = g_h[o * D_IN + t];
            const float w0 = g_w[o * D_IN + t];
            const int   h1 = g_h[o * D_IN + t + 512];
            const float w1 = g_w[o * D_IN + t + 512];
            atomicAdd(&bre[h0], w0 * xv0);
            atomicAdd(&bre[h1], w1 * xv1);
        }
        __syncthreads();
        // ---- load layout A (thread t holds X[t + 512*j]), imag = 0 ----
#pragma unroll
        for (int j = 0; j < 16; ++j) { Xre[j] = bre[t + 512 * j]; Xim[j] = 0.0f; }

        // ---- phase A: DIF stages lh=12..9 (m=3..0), pairs along j ----
#pragma unroll
        for (int m = 3; m >= 0; --m) {
            const int half = 1 << m;
#pragma unroll
            for (int p = 0; p < 8; ++p) {
                const int lo = p & (half - 1);
                const int hi = p >> m;
                const int j0 = (hi << (m + 1)) + lo;
                const int j1 = j0 + half;
                const int k  = (t + 512 * lo) << (3 - m);
                const float2 w = g_tw[k];
                float ar = Xre[j0], ai = Xim[j0];
                float br = Xre[j1], bi = Xim[j1];
                Xre[j0] = ar + br; Xim[j0] = ai + bi;
                float dr = ar - br, di = ai - bi;
                Xre[j1] = dr * w.x - di * w.y;
                Xim[j1] = dr * w.y + di * w.x;
            }
        }

        // ---- exchange A->B (write own natural slots, read 512b+s+32j) ----
#pragma unroll
        for (int j = 0; j < 16; ++j) { bre[t + 512 * j] = Xre[j]; bim[t + 512 * j] = Xim[j]; }
        __syncthreads();
#pragma unroll
        for (int j = 0; j < 16; ++j) { Xre[j] = bre[base + 32 * j]; Xim[j] = bim[base + 32 * j]; }
        __syncthreads();   // buffer free for next order / inverse

        // ---- phase B: DIF stages lh=8..5 (m=3..0), pairs along j ----
#pragma unroll
        for (int m = 3; m >= 0; --m) {
            const int half = 1 << m;
#pragma unroll
            for (int p = 0; p < 8; ++p) {
                const int lo = p & (half - 1);
                const int hi = p >> m;
                const int j0 = (hi << (m + 1)) + lo;
                const int j1 = j0 + half;
                const int k  = (s + 32 * lo) << (7 - m);
                const float2 w = g_tw[k];
                float ar = Xre[j0], ai = Xim[j0];
                float br = Xre[j1], bi = Xim[j1];
                Xre[j0] = ar + br; Xim[j0] = ai + bi;
                float dr = ar - br, di = ai - bi;
                Xre[j1] = dr * w.x - di * w.y;
                Xim[j1] = dr * w.y + di * w.x;
            }
        }

        // ---- phase C: DIF stages lh=4..0, cross-lane in s via shfl_xor ----
#pragma unroll
        for (int lh = 4; lh >= 0; --lh) {
            const int st = 1 << lh;
            const int k  = (s & (st - 1)) << (12 - lh);
            float2 w = g_tw[k];
            const bool up = (s & st) != 0;
            const float sg = up ? -1.0f : 1.0f;
            if (!up) { w.x = 1.0f; w.y = 0.0f; }
#pragma unroll
            for (int j = 0; j < 16; ++j) {
                float pr = __shfl_xor(Xre[j], st, 64);
                float pi = __shfl_xor(Xim[j], st, 64);
                float tr = pr + sg * Xre[j];
                float ti = pi + sg * Xim[j];
                Xre[j] = tr * w.x - ti * w.y;
                Xim[j] = tr * w.y + ti * w.x;
            }
        }

        // ---- accumulate spectral product (bit-reversed order OK) ----
        if (o == 0) {
#pragma unroll
            for (int j = 0; j < 16; ++j) { Pre[j] = Xre[j]; Pim[j] = Xim[j]; }
        } else {
#pragma unroll
            for (int j = 0; j < 16; ++j) {
                float ar = Pre[j], ai = Pim[j];
                Pre[j] = ar * Xre[j] - ai * Xim[j];
                Pim[j] = ar * Xim[j] + ai * Xre[j];
            }
        }
    }

    // ================= inverse DIT =================
    // stages lh=0..4: cross-lane in s (pre-multiply upper lane by conj twiddle)
#pragma unroll
    for (int lh = 0; lh <= 4; ++lh) {
        const int st = 1 << lh;
        const int k  = (s & (st - 1)) << (12 - lh);
        float2 w = g_tw[k];
        w.y = -w.y;                        // conj
        const bool up = (s & st) != 0;
        const float sg = up ? -1.0f : 1.0f;
        if (!up) { w.x = 1.0f; w.y = 0.0f; }
#pragma unroll
        for (int j = 0; j < 16; ++j) {
            float er = Pre[j] * w.x - Pim[j] * w.y;
            float ei = Pre[j] * w.y + Pim[j] * w.x;
            float pr = __shfl_xor(er, st, 64);
            float pi = __shfl_xor(ei, st, 64);
            Pre[j] = pr + sg * er;
            Pim[j] = pi + sg * ei;
        }
    }

    // stages lh=5..8 (m=0..3), pairs along j in layout B
#pragma unroll
    for (int m = 0; m <= 3; ++m) {
        const int half = 1 << m;
#pragma unroll
        for (int p = 0; p < 8; ++p) {
            const int lo = p & (half - 1);
            const int hi = p >> m;
            const int j0 = (hi << (m + 1)) + lo;
            const int j1 = j0 + half;
            const int k  = (s + 32 * lo) << (7 - m);
            float2 w = g_tw[k];
            float tr = Pre[j1] * w.x + Pim[j1] * w.y;   // mul by conj(w)
            float ti = Pim[j1] * w.x - Pre[j1] * w.y;
            Pre[j1] = Pre[j0] - tr; Pim[j1] = Pim[j0] - ti;
            Pre[j0] += tr; Pim[j0] += ti;
        }
    }

    // exchange B->A
#pragma unroll
    for (int j = 0; j < 16; ++j) { bre[base + 32 * j] = Pre[j]; bim[base + 32 * j] = Pim[j]; }
    __syncthreads();
#pragma unroll
    for (int j = 0; j < 16; ++j) { Pre[j] = bre[t + 512 * j]; Pim[j] = bim[t + 512 * j]; }

    // stages lh=9..12 (m=0..3), pairs along j in layout A
#pragma unroll
    for (int m = 0; m <= 3; ++m) {
        const int half = 1 << m;
#pragma unroll
        for (int p = 0; p < 8; ++p) {
            const int lo = p & (half - 1);
            const int hi = p >> m;
            const int j0 = (hi << (m + 1)) + lo;
            const int j1 = j0 + half;
            const int k  = (t + 512 * lo) << (3 - m);
            float2 w = g_tw[k];
            float tr = Pre[j1] * w.x + Pim[j1] * w.y;   // mul by conj(w)
            float ti = Pim[j1] * w.x - Pre[j1] * w.y;
            Pre[j1] = Pre[j0] - tr; Pim[j1] = Pim[j0] - ti;
            Pre[j0] += tr; Pim[j0] += ti;
        }
    }

    const float scale = 1.0f / (float)D_OUTD;
    if (staged) {
#pragma unroll
        for (int j = 0; j < 16; ++j)
            outbuf[n * D_OUTD + t + 512 * j] = Pre[j] * scale;
    } else {
#pragma unroll
        for (int j = 0; j < 16; ++j)
            outbuf[(t + 512 * j) * NCOL + n] = Pre[j] * scale;
    }
}

// [N][D_out] -> [D_out][N], 32x32 tiles
__global__ void transpose_kernel(const float* __restrict__ in, float* __restrict__ out) {
    __shared__ float tile[32][33];
    int d0 = blockIdx.x * 32;
    int n0 = blockIdx.y * 32;
    int tx = threadIdx.x;
    int ty = threadIdx.y;
#pragma unroll
    for (int j = 0; j < 32; j += 8)
        tile[ty + j][tx] = in[(n0 + ty + j) * D_OUTD + d0 + tx];
    __syncthreads();
#pragma unroll
    for (int j = 0; j < 32; j += 8)
        out[(d0 + ty + j) * NCOL + n0 + tx] = tile[tx][ty + j];
}

extern "C" void kernel_launch(void* const* d_in, const int* in_sizes, int n_in,
                              void* d_out, int out_size, void* d_ws, size_t ws_size,
                              hipStream_t stream) {
    (void)in_sizes; (void)n_in; (void)out_size;
    const float* x     = (const float*)d_in[0];
    const float* hmaps = (const float*)d_in[1];
    float* out = (float*)d_out;

    tw_kernel<<<(D_OUTD / 2 + 255) / 256, 256, 0, stream>>>();
    extract_kernel<<<(ORDER * D_OUTD * D_IN + 255) / 256, 256, 0, stream>>>(hmaps);

    size_t need = (size_t)NCOL * D_OUTD * sizeof(float);
    if (ws_size >= need) {
        float* stag = (float*)d_ws;
        sketch_kernel<<<NCOL, 512, 0, stream>>>(x, stag, 1);
        transpose_kernel<<<dim3(D_OUTD / 32, NCOL / 32), dim3(32, 8), 0, stream>>>(stag, out);
    } else {
        sketch_kernel<<<NCOL, 512, 0, stream>>>(x, out, 0);
    }
}

// Round 3
// 364.597 us; speedup vs baseline: 1.7988x; 1.4451x over previous
//
#include <hip/hip_runtime.h>

#define D_IN   1024
#define D_OUTD 8192
#define ORDER  3
#define NCOL   2048

// Persistent device-side tables (rewritten every kernel_launch call).
__device__ float2 g_tw[D_OUTD / 2];      // W_8192^k, k in [0,4096)
__device__ int    g_h[ORDER * D_IN];
__device__ float  g_w[ORDER * D_IN];

__global__ void tw_kernel() {
    int k = blockIdx.x * 256 + threadIdx.x;
    if (k < D_OUTD / 2) {
        double ang = -2.0 * 3.14159265358979323846 * (double)k / (double)D_OUTD;
        g_tw[k] = make_float2((float)cos(ang), (float)sin(ang));
    }
}

__global__ void extract_kernel(const float* __restrict__ hmaps) {
    int idx = blockIdx.x * 256 + threadIdx.x;
    if (idx >= ORDER * D_OUTD * D_IN) return;
    float v = hmaps[idx];
    if (v != 0.0f) {
        int i   = idx % D_IN;
        int rem = idx / D_IN;
        int d   = rem % D_OUTD;
        int o   = rem / D_OUTD;
        g_h[o * D_IN + i] = d;
        g_w[o * D_IN + i] = v;
    }
}

// x [D_IN][N] -> xT [N][D_IN] so sketch blocks read a contiguous 4KB column.
__global__ void xt_kernel(const float* __restrict__ in, float* __restrict__ out) {
    __shared__ float tile[32][33];
    int i0 = blockIdx.x * 32;
    int n0 = blockIdx.y * 32;
    int tx = threadIdx.x;
    int ty = threadIdx.y;
#pragma unroll
    for (int j = 0; j < 32; j += 8)
        tile[ty + j][tx] = in[(i0 + ty + j) * NCOL + n0 + tx];
    __syncthreads();
#pragma unroll
    for (int j = 0; j < 32; j += 8)
        out[(n0 + ty + j) * D_IN + i0 + tx] = tile[tx][ty + j];
}

// 512 threads per column n. 16 complex points per thread, register-resident FFT.
// Forward DIF: phase A (strides 4096..512, reg) -> LDS exchange -> phase B
// (256..32, reg) -> phase C (16..1, shfl_xor). Product in registers.
// Inverse DIT mirrors it.
// launch_bounds (512,2): VGPR cap 256 -- (512,4) capped at 128 and spilled
// ~1.1 GB of scratch per dispatch (round-2 FETCH_SIZE blowup).
__launch_bounds__(512, 2)
__global__ void sketch_kernel(const float* __restrict__ x, float* __restrict__ outbuf,
                              int staged, int xcoal) {
    __shared__ float bre[D_OUTD];
    __shared__ float bim[D_OUTD];
    const int n = blockIdx.x;
    const int t = threadIdx.x;
    const int s = t & 31;
    const int base = ((t >> 5) << 9) + s;   // 512*b + s

    float xv0, xv1;
    if (xcoal) {
        xv0 = x[n * D_IN + t];
        xv1 = x[n * D_IN + t + 512];
    } else {
        xv0 = x[t * NCOL + n];
        xv1 = x[(t + 512) * NCOL + n];
    }

    float Pre[16], Pim[16];
    float Xre[16], Xim[16];

    for (int o = 0; o < ORDER; ++o) {
        // ---- scatter count[o][.] into bre ----
#pragma unroll
        for (int j = 0; j < 16; ++j) bre[t + 512 * j] = 0.0f;
        __syncthreads();
        {
            const int   h0 = g_h[o * D_IN + t];
            const float w0 = g_w[o * D_IN + t];
            const int   h1 = g_h[o * D_IN + t + 512];
            const float w1 = g_w[o * D_IN + t + 512];
            atomicAdd(&bre[h0], w0 * xv0);
            atomicAdd(&bre[h1], w1 * xv1);
        }
        __syncthreads();
        // ---- load layout A (thread t holds X[t + 512*j]), imag = 0 ----
#pragma unroll
        for (int j = 0; j < 16; ++j) { Xre[j] = bre[t + 512 * j]; Xim[j] = 0.0f; }

        // ---- phase A: DIF stages lh=12..9 (m=3..0), pairs along j ----
#pragma unroll
        for (int m = 3; m >= 0; --m) {
            const int half = 1 << m;
#pragma unroll
            for (int p = 0; p < 8; ++p) {
                const int lo = p & (half - 1);
                const int hi = p >> m;
                const int j0 = (hi << (m + 1)) + lo;
                const int j1 = j0 + half;
                const int k  = (t + 512 * lo) << (3 - m);
                const float2 w = g_tw[k];
                float ar = Xre[j0], ai = Xim[j0];
                float br = Xre[j1], bi = Xim[j1];
                Xre[j0] = ar + br; Xim[j0] = ai + bi;
                float dr = ar - br, di = ai - bi;
                Xre[j1] = dr * w.x - di * w.y;
                Xim[j1] = dr * w.y + di * w.x;
            }
        }

        // ---- exchange A->B (write own natural slots, read 512b+s+32j) ----
#pragma unroll
        for (int j = 0; j < 16; ++j) { bre[t + 512 * j] = Xre[j]; bim[t + 512 * j] = Xim[j]; }
        __syncthreads();
#pragma unroll
        for (int j = 0; j < 16; ++j) { Xre[j] = bre[base + 32 * j]; Xim[j] = bim[base + 32 * j]; }
        __syncthreads();   // buffer free for next order / inverse

        // ---- phase B: DIF stages lh=8..5 (m=3..0), pairs along j ----
#pragma unroll
        for (int m = 3; m >= 0; --m) {
            const int half = 1 << m;
#pragma unroll
            for (int p = 0; p < 8; ++p) {
                const int lo = p & (half - 1);
                const int hi = p >> m;
                const int j0 = (hi << (m + 1)) + lo;
                const int j1 = j0 + half;
                const int k  = (s + 32 * lo) << (7 - m);
                const float2 w = g_tw[k];
                float ar = Xre[j0], ai = Xim[j0];
                float br = Xre[j1], bi = Xim[j1];
                Xre[j0] = ar + br; Xim[j0] = ai + bi;
                float dr = ar - br, di = ai - bi;
                Xre[j1] = dr * w.x - di * w.y;
                Xim[j1] = dr * w.y + di * w.x;
            }
        }

        // ---- phase C: DIF stages lh=4..0, cross-lane in s via shfl_xor ----
#pragma unroll
        for (int lh = 4; lh >= 0; --lh) {
            const int st = 1 << lh;
            const int k  = (s & (st - 1)) << (12 - lh);
            float2 w = g_tw[k];
            const bool up = (s & st) != 0;
            const float sg = up ? -1.0f : 1.0f;
            if (!up) { w.x = 1.0f; w.y = 0.0f; }
#pragma unroll
            for (int j = 0; j < 16; ++j) {
                float pr = __shfl_xor(Xre[j], st, 64);
                float pi = __shfl_xor(Xim[j], st, 64);
                float tr = pr + sg * Xre[j];
                float ti = pi + sg * Xim[j];
                Xre[j] = tr * w.x - ti * w.y;
                Xim[j] = tr * w.y + ti * w.x;
            }
        }

        // ---- accumulate spectral product (bit-reversed order OK) ----
        if (o == 0) {
#pragma unroll
            for (int j = 0; j < 16; ++j) { Pre[j] = Xre[j]; Pim[j] = Xim[j]; }
        } else {
#pragma unroll
            for (int j = 0; j < 16; ++j) {
                float ar = Pre[j], ai = Pim[j];
                Pre[j] = ar * Xre[j] - ai * Xim[j];
                Pim[j] = ar * Xim[j] + ai * Xre[j];
            }
        }
    }

    // ================= inverse DIT =================
    // stages lh=0..4: cross-lane in s (pre-multiply by conj twiddle)
#pragma unroll
    for (int lh = 0; lh <= 4; ++lh) {
        const int st = 1 << lh;
        const int k  = (s & (st - 1)) << (12 - lh);
        float2 w = g_tw[k];
        w.y = -w.y;                        // conj
        const bool up = (s & st) != 0;
        const float sg = up ? -1.0f : 1.0f;
        if (!up) { w.x = 1.0f; w.y = 0.0f; }
#pragma unroll
        for (int j = 0; j < 16; ++j) {
            float er = Pre[j] * w.x - Pim[j] * w.y;
            float ei = Pre[j] * w.y + Pim[j] * w.x;
            float pr = __shfl_xor(er, st, 64);
            float pi = __shfl_xor(ei, st, 64);
            Pre[j] = pr + sg * er;
            Pim[j] = pi + sg * ei;
        }
    }

    // stages lh=5..8 (m=0..3), pairs along j in layout B
#pragma unroll
    for (int m = 0; m <= 3; ++m) {
        const int half = 1 << m;
#pragma unroll
        for (int p = 0; p < 8; ++p) {
            const int lo = p & (half - 1);
            const int hi = p >> m;
            const int j0 = (hi << (m + 1)) + lo;
            const int j1 = j0 + half;
            const int k  = (s + 32 * lo) << (7 - m);
            float2 w = g_tw[k];
            float tr = Pre[j1] * w.x + Pim[j1] * w.y;   // mul by conj(w)
            float ti = Pim[j1] * w.x - Pre[j1] * w.y;
            Pre[j1] = Pre[j0] - tr; Pim[j1] = Pim[j0] - ti;
            Pre[j0] += tr; Pim[j0] += ti;
        }
    }

    // exchange B->A
#pragma unroll
    for (int j = 0; j < 16; ++j) { bre[base + 32 * j] = Pre[j]; bim[base + 32 * j] = Pim[j]; }
    __syncthreads();
#pragma unroll
    for (int j = 0; j < 16; ++j) { Pre[j] = bre[t + 512 * j]; Pim[j] = bim[t + 512 * j]; }

    // stages lh=9..12 (m=0..3), pairs along j in layout A
#pragma unroll
    for (int m = 0; m <= 3; ++m) {
        const int half = 1 << m;
#pragma unroll
        for (int p = 0; p < 8; ++p) {
            const int lo = p & (half - 1);
            const int hi = p >> m;
            const int j0 = (hi << (m + 1)) + lo;
            const int j1 = j0 + half;
            const int k  = (t + 512 * lo) << (3 - m);
            float2 w = g_tw[k];
            float tr = Pre[j1] * w.x + Pim[j1] * w.y;   // mul by conj(w)
            float ti = Pim[j1] * w.x - Pre[j1] * w.y;
            Pre[j1] = Pre[j0] - tr; Pim[j1] = Pim[j0] - ti;
            Pre[j0] += tr; Pim[j0] += ti;
        }
    }

    const float scale = 1.0f / (float)D_OUTD;
    if (staged) {
#pragma unroll
        for (int j = 0; j < 16; ++j)
            outbuf[n * D_OUTD + t + 512 * j] = Pre[j] * scale;
    } else {
#pragma unroll
        for (int j = 0; j < 16; ++j)
            outbuf[(t + 512 * j) * NCOL + n] = Pre[j] * scale;
    }
}

// [N][D_out] -> [D_out][N], 32x32 tiles
__global__ void transpose_kernel(const float* __restrict__ in, float* __restrict__ out) {
    __shared__ float tile[32][33];
    int d0 = blockIdx.x * 32;
    int n0 = blockIdx.y * 32;
    int tx = threadIdx.x;
    int ty = threadIdx.y;
#pragma unroll
    for (int j = 0; j < 32; j += 8)
        tile[ty + j][tx] = in[(n0 + ty + j) * D_OUTD + d0 + tx];
    __syncthreads();
#pragma unroll
    for (int j = 0; j < 32; j += 8)
        out[(d0 + ty + j) * NCOL + n0 + tx] = tile[tx][ty + j];
}

extern "C" void kernel_launch(void* const* d_in, const int* in_sizes, int n_in,
                              void* d_out, int out_size, void* d_ws, size_t ws_size,
                              hipStream_t stream) {
    (void)in_sizes; (void)n_in; (void)out_size;
    const float* x     = (const float*)d_in[0];
    const float* hmaps = (const float*)d_in[1];
    float* out = (float*)d_out;

    tw_kernel<<<(D_OUTD / 2 + 255) / 256, 256, 0, stream>>>();
    extract_kernel<<<(ORDER * D_OUTD * D_IN + 255) / 256, 256, 0, stream>>>(hmaps);

    const size_t stage_bytes = (size_t)NCOL * D_OUTD * sizeof(float);
    const size_t xt_bytes    = (size_t)NCOL * D_IN * sizeof(float);

    const float* xs = x;
    int xcoal = 0;
    if (ws_size >= stage_bytes + xt_bytes) {
        float* xT = (float*)((char*)d_ws + stage_bytes);
        xt_kernel<<<dim3(D_IN / 32, NCOL / 32), dim3(32, 8), 0, stream>>>(x, xT);
        xs = xT;
        xcoal = 1;
    }

    if (ws_size >= stage_bytes) {
        float* stag = (float*)d_ws;
        sketch_kernel<<<NCOL, 512, 0, stream>>>(xs, stag, 1, xcoal);
        transpose_kernel<<<dim3(D_OUTD / 32, NCOL / 32), dim3(32, 8), 0, stream>>>(stag, out);
    } else {
        sketch_kernel<<<NCOL, 512, 0, stream>>>(xs, out, 0, xcoal);
    }
}

// Round 4
// 324.465 us; speedup vs baseline: 2.0213x; 1.1237x over previous
//
#include <hip/hip_runtime.h>

#define D_IN   1024
#define D_OUTD 8192
#define ORDER  3
#define NCOL   2048

// Persistent device-side tables (rewritten every kernel_launch call).
__device__ float2 g_tw[D_OUTD / 2];      // W_8192^k, k in [0,4096)
__device__ int    g_h[ORDER * D_IN];
__device__ float  g_w[ORDER * D_IN];

__global__ void tw_kernel() {
    int k = blockIdx.x * 256 + threadIdx.x;
    if (k < D_OUTD / 2) {
        double ang = -2.0 * 3.14159265358979323846 * (double)k / (double)D_OUTD;
        g_tw[k] = make_float2((float)cos(ang), (float)sin(ang));
    }
}

__global__ void extract_kernel(const float* __restrict__ hmaps) {
    int idx = blockIdx.x * 256 + threadIdx.x;
    if (idx >= ORDER * D_OUTD * D_IN) return;
    float v = hmaps[idx];
    if (v != 0.0f) {
        int i   = idx % D_IN;
        int rem = idx / D_IN;
        int d   = rem % D_OUTD;
        int o   = rem / D_OUTD;
        g_h[o * D_IN + i] = d;
        g_w[o * D_IN + i] = v;
    }
}

// x [D_IN][N] -> xT [N][D_IN] so sketch blocks read a contiguous 4KB column.
__global__ void xt_kernel(const float* __restrict__ in, float* __restrict__ out) {
    __shared__ float tile[32][33];
    int i0 = blockIdx.x * 32;
    int n0 = blockIdx.y * 32;
    int tx = threadIdx.x;
    int ty = threadIdx.y;
#pragma unroll
    for (int j = 0; j < 32; j += 8)
        tile[ty + j][tx] = in[(i0 + ty + j) * NCOL + n0 + tx];
    __syncthreads();
#pragma unroll
    for (int j = 0; j < 32; j += 8)
        out[(n0 + ty + j) * D_IN + i0 + tx] = tile[tx][ty + j];
}

__device__ __forceinline__ float2 cmul(float2 a, float2 b) {
    return make_float2(a.x * b.x - a.y * b.y, a.x * b.y + a.y * b.x);
}
__device__ __forceinline__ float2 csqr(float2 a) {
    return make_float2(a.x * a.x - a.y * a.y, 2.0f * a.x * a.y);
}
// compile-time 16th roots of unity: e^{-2*pi*i*k/16}, k=0..7
__device__ __forceinline__ float2 c16(int k) {
    constexpr float R[8] = { 1.0f,  0.92387953251128674f,  0.70710678118654757f,  0.38268343236508978f,
                             0.0f, -0.38268343236508978f, -0.70710678118654757f, -0.92387953251128674f };
    constexpr float I[8] = { 0.0f, -0.38268343236508978f, -0.70710678118654757f, -0.92387953251128674f,
                            -1.0f, -0.92387953251128674f, -0.70710678118654757f, -0.38268343236508978f };
    return make_float2(R[k], I[k]);
}

// 512 threads per column n, 16 complex points per thread, register-resident FFT.
// ALL twiddles are computed in registers (squaring chains from 3 coalesced seed
// loads + compile-time 16th-root constants) -- round-3 profile implied the
// per-butterfly g_tw[] gathers (up to 64 cacheline splits per wave64 load)
// were the bottleneck.
__launch_bounds__(512, 2)
__global__ void sketch_kernel(const float* __restrict__ x, float* __restrict__ outbuf,
                              int staged, int xcoal) {
    __shared__ float bre[D_OUTD];
    __shared__ float bim[D_OUTD];
    const int n = blockIdx.x;
    const int t = threadIdx.x;
    const int s = t & 31;
    const int base = ((t >> 5) << 9) + s;   // 512*b + s

    float xv0, xv1;
    if (xcoal) {
        xv0 = x[n * D_IN + t];
        xv1 = x[n * D_IN + t + 512];
    } else {
        xv0 = x[t * NCOL + n];
        xv1 = x[(t + 512) * NCOL + n];
    }

    // ---- twiddle seeds (coalesced loads) + register chains ----
    const float2 wt  = g_tw[t];        // W^t
    const float2 ws  = g_tw[s];        // W^s
    const float2 w15 = g_tw[s & 15];   // W^(s&15)
    const float2 bb16 = csqr(csqr(csqr(csqr(ws))));           // W^(16s)
    float2 t4 = w15;                                           // -> W^(256*(s&15))
#pragma unroll
    for (int q = 0; q < 8; ++q) t4 = csqr(t4);
    const float sg3 = ((s >> 3) & 1) ? -1.0f : 1.0f;
    const float sg2 = ((s >> 2) & 1) ? -1.0f : 1.0f;
    const float sg1 = ((s >> 1) & 1) ? -1.0f : 1.0f;
    float2 t3 = csqr(t4); t3.x *= sg3; t3.y *= sg3;            // W^(512*(s&7))
    float2 t2 = csqr(t3); t2.x *= sg2; t2.y *= sg2;            // W^(1024*(s&3))
    float2 t1 = csqr(t2); t1.x *= sg1; t1.y *= sg1;            // W^(2048*(s&1))
    const float2 tc[5] = { make_float2(1.0f, 0.0f), t1, t2, t3, t4 };

    float Pre[16], Pim[16];
    float Xre[16], Xim[16];

    for (int o = 0; o < ORDER; ++o) {
        // ---- scatter count[o][.] into bre ----
#pragma unroll
        for (int j = 0; j < 16; ++j) bre[t + 512 * j] = 0.0f;
        __syncthreads();
        {
            const int   h0 = g_h[o * D_IN + t];
            const float w0 = g_w[o * D_IN + t];
            const int   h1 = g_h[o * D_IN + t + 512];
            const float w1 = g_w[o * D_IN + t + 512];
            atomicAdd(&bre[h0], w0 * xv0);
            atomicAdd(&bre[h1], w1 * xv1);
        }
        __syncthreads();
#pragma unroll
        for (int j = 0; j < 16; ++j) { Xre[j] = bre[t + 512 * j]; Xim[j] = 0.0f; }

        // ---- phase A: DIF stages, pairs along j, twiddles from wt chain ----
        {
            float2 ba = wt;
#pragma unroll
            for (int m = 3; m >= 0; --m) {
                const int half = 1 << m;
                float2 tw[8];
#pragma unroll
                for (int lo = 0; lo < half; ++lo) tw[lo] = cmul(ba, c16(lo << (3 - m)));
#pragma unroll
                for (int p = 0; p < 8; ++p) {
                    const int lo = p & (half - 1);
                    const int hi = p >> m;
                    const int j0 = (hi << (m + 1)) + lo;
                    const int j1 = j0 + half;
                    const float2 w = tw[lo];
                    float ar = Xre[j0], ai = Xim[j0];
                    float br = Xre[j1], bi = Xim[j1];
                    Xre[j0] = ar + br; Xim[j0] = ai + bi;
                    float dr = ar - br, di = ai - bi;
                    Xre[j1] = dr * w.x - di * w.y;
                    Xim[j1] = dr * w.y + di * w.x;
                }
                if (m) ba = csqr(ba);
            }
        }

        // ---- exchange A->B ----
#pragma unroll
        for (int j = 0; j < 16; ++j) { bre[t + 512 * j] = Xre[j]; bim[t + 512 * j] = Xim[j]; }
        __syncthreads();
#pragma unroll
        for (int j = 0; j < 16; ++j) { Xre[j] = bre[base + 32 * j]; Xim[j] = bim[base + 32 * j]; }
        __syncthreads();

        // ---- phase B: twiddles from bb16 chain ----
        {
            float2 bb = bb16;
#pragma unroll
            for (int m = 3; m >= 0; --m) {
                const int half = 1 << m;
                float2 tw[8];
#pragma unroll
                for (int lo = 0; lo < half; ++lo) tw[lo] = cmul(bb, c16(lo << (3 - m)));
#pragma unroll
                for (int p = 0; p < 8; ++p) {
                    const int lo = p & (half - 1);
                    const int hi = p >> m;
                    const int j0 = (hi << (m + 1)) + lo;
                    const int j1 = j0 + half;
                    const float2 w = tw[lo];
                    float ar = Xre[j0], ai = Xim[j0];
                    float br = Xre[j1], bi = Xim[j1];
                    Xre[j0] = ar + br; Xim[j0] = ai + bi;
                    float dr = ar - br, di = ai - bi;
                    Xre[j1] = dr * w.x - di * w.y;
                    Xim[j1] = dr * w.y + di * w.x;
                }
                if (m) bb = csqr(bb);
            }
        }

        // ---- phase C: cross-lane shfl_xor, twiddles tc[lh] ----
#pragma unroll
        for (int lh = 4; lh >= 0; --lh) {
            const int st = 1 << lh;
            float2 w = tc[lh];
            const bool up = (s & st) != 0;
            const float sg = up ? -1.0f : 1.0f;
            if (!up) { w.x = 1.0f; w.y = 0.0f; }
#pragma unroll
            for (int j = 0; j < 16; ++j) {
                float pr = __shfl_xor(Xre[j], st, 64);
                float pi = __shfl_xor(Xim[j], st, 64);
                float tr = pr + sg * Xre[j];
                float ti = pi + sg * Xim[j];
                Xre[j] = tr * w.x - ti * w.y;
                Xim[j] = tr * w.y + ti * w.x;
            }
        }

        // ---- accumulate spectral product ----
        if (o == 0) {
#pragma unroll
            for (int j = 0; j < 16; ++j) { Pre[j] = Xre[j]; Pim[j] = Xim[j]; }
        } else {
#pragma unroll
            for (int j = 0; j < 16; ++j) {
                float ar = Pre[j], ai = Pim[j];
                Pre[j] = ar * Xre[j] - ai * Xim[j];
                Pim[j] = ar * Xim[j] + ai * Xre[j];
            }
        }
    }

    // ================= inverse DIT =================
    // phase C inverse: lh=0..4, conj(tc[lh])
#pragma unroll
    for (int lh = 0; lh <= 4; ++lh) {
        const int st = 1 << lh;
        float2 w = tc[lh];
        w.y = -w.y;
        const bool up = (s & st) != 0;
        const float sg = up ? -1.0f : 1.0f;
        if (!up) { w.x = 1.0f; w.y = 0.0f; }
#pragma unroll
        for (int j = 0; j < 16; ++j) {
            float er = Pre[j] * w.x - Pim[j] * w.y;
            float ei = Pre[j] * w.y + Pim[j] * w.x;
            float pr = __shfl_xor(er, st, 64);
            float pi = __shfl_xor(ei, st, 64);
            Pre[j] = pr + sg * er;
            Pim[j] = pi + sg * ei;
        }
    }

    // phase B inverse: bases bb128..bb16 (forward values; butterfly conjugates inline)
    {
        const float2 bb32 = csqr(bb16), bb64 = csqr(bb32), bb128 = csqr(bb64);
        const float2 bbs[4] = { bb128, bb64, bb32, bb16 };
#pragma unroll
        for (int m = 0; m <= 3; ++m) {
            const int half = 1 << m;
            float2 tw[8];
#pragma unroll
            for (int lo = 0; lo < half; ++lo) tw[lo] = cmul(bbs[m], c16(lo << (3 - m)));
#pragma unroll
            for (int p = 0; p < 8; ++p) {
                const int lo = p & (half - 1);
                const int hi = p >> m;
                const int j0 = (hi << (m + 1)) + lo;
                const int j1 = j0 + half;
                const float2 w = tw[lo];
                float tr = Pre[j1] * w.x + Pim[j1] * w.y;   // mul by conj(w)
                float ti = Pim[j1] * w.x - Pre[j1] * w.y;
                Pre[j1] = Pre[j0] - tr; Pim[j1] = Pim[j0] - ti;
                Pre[j0] += tr; Pim[j0] += ti;
            }
        }
    }

    // exchange B->A
#pragma unroll
    for (int j = 0; j < 16; ++j) { bre[base + 32 * j] = Pre[j]; bim[base + 32 * j] = Pim[j]; }
    __syncthreads();
#pragma unroll
    for (int j = 0; j < 16; ++j) { Pre[j] = bre[t + 512 * j]; Pim[j] = bim[t + 512 * j]; }

    // phase A inverse: bases wt^8..wt^1
    {
        const float2 ba2 = csqr(wt), ba4 = csqr(ba2), ba8 = csqr(ba4);
        const float2 bas[4] = { ba8, ba4, ba2, wt };
#pragma unroll
        for (int m = 0; m <= 3; ++m) {
            const int half = 1 << m;
            float2 tw[8];
#pragma unroll
            for (int lo = 0; lo < half; ++lo) tw[lo] = cmul(bas[m], c16(lo << (3 - m)));
#pragma unroll
            for (int p = 0; p < 8; ++p) {
                const int lo = p & (half - 1);
                const int hi = p >> m;
                const int j0 = (hi << (m + 1)) + lo;
                const int j1 = j0 + half;
                const float2 w = tw[lo];
                float tr = Pre[j1] * w.x + Pim[j1] * w.y;   // mul by conj(w)
                float ti = Pim[j1] * w.x - Pre[j1] * w.y;
                Pre[j1] = Pre[j0] - tr; Pim[j1] = Pim[j0] - ti;
                Pre[j0] += tr; Pim[j0] += ti;
            }
        }
    }

    const float scale = 1.0f / (float)D_OUTD;
    if (staged) {
#pragma unroll
        for (int j = 0; j < 16; ++j)
            outbuf[n * D_OUTD + t + 512 * j] = Pre[j] * scale;
    } else {
#pragma unroll
        for (int j = 0; j < 16; ++j)
            outbuf[(t + 512 * j) * NCOL + n] = Pre[j] * scale;
    }
}

// [N][D_out] -> [D_out][N], 32x32 tiles
__global__ void transpose_kernel(const float* __restrict__ in, float* __restrict__ out) {
    __shared__ float tile[32][33];
    int d0 = blockIdx.x * 32;
    int n0 = blockIdx.y * 32;
    int tx = threadIdx.x;
    int ty = threadIdx.y;
#pragma unroll
    for (int j = 0; j < 32; j += 8)
        tile[ty + j][tx] = in[(n0 + ty + j) * D_OUTD + d0 + tx];
    __syncthreads();
#pragma unroll
    for (int j = 0; j < 32; j += 8)
        out[(d0 + ty + j) * NCOL + n0 + tx] = tile[tx][ty + j];
}

extern "C" void kernel_launch(void* const* d_in, const int* in_sizes, int n_in,
                              void* d_out, int out_size, void* d_ws, size_t ws_size,
                              hipStream_t stream) {
    (void)in_sizes; (void)n_in; (void)out_size;
    const float* x     = (const float*)d_in[0];
    const float* hmaps = (const float*)d_in[1];
    float* out = (float*)d_out;

    tw_kernel<<<(D_OUTD / 2 + 255) / 256, 256, 0, stream>>>();
    extract_kernel<<<(ORDER * D_OUTD * D_IN + 255) / 256, 256, 0, stream>>>(hmaps);

    const size_t stage_bytes = (size_t)NCOL * D_OUTD * sizeof(float);
    const size_t xt_bytes    = (size_t)NCOL * D_IN * sizeof(float);

    const float* xs = x;
    int xcoal = 0;
    if (ws_size >= stage_bytes + xt_bytes) {
        float* xT = (float*)((char*)d_ws + stage_bytes);
        xt_kernel<<<dim3(D_IN / 32, NCOL / 32), dim3(32, 8), 0, stream>>>(x, xT);
        xs = xT;
        xcoal = 1;
    }

    if (ws_size >= stage_bytes) {
        float* stag = (float*)d_ws;
        sketch_kernel<<<NCOL, 512, 0, stream>>>(xs, stag, 1, xcoal);
        transpose_kernel<<<dim3(D_OUTD / 32, NCOL / 32), dim3(32, 8), 0, stream>>>(stag, out);
    } else {
        sketch_kernel<<<NCOL, 512, 0, stream>>>(xs, out, 0, xcoal);
    }
}

// Round 5
// 231.028 us; speedup vs baseline: 2.8388x; 1.4044x over previous
//
#include <hip/hip_runtime.h>

#define D_IN   1024
#define D_OUTD 8192
#define ORDER  3
#define NCOL   2048

// Persistent device-side tables (rewritten every kernel_launch call).
__device__ float2 g_tw[D_OUTD / 2];      // W_8192^k, k in [0,4096)
__device__ int    g_h[ORDER * D_IN];
__device__ float  g_w[ORDER * D_IN];

__global__ void tw_kernel() {
    int k = blockIdx.x * 256 + threadIdx.x;
    if (k < D_OUTD / 2) {
        double ang = -2.0 * 3.14159265358979323846 * (double)k / (double)D_OUTD;
        g_tw[k] = make_float2((float)cos(ang), (float)sin(ang));
    }
}

__global__ void extract_kernel(const float* __restrict__ hmaps) {
    int idx = blockIdx.x * 256 + threadIdx.x;
    if (idx >= ORDER * D_OUTD * D_IN) return;
    float v = hmaps[idx];
    if (v != 0.0f) {
        int i   = idx % D_IN;
        int rem = idx / D_IN;
        int d   = rem % D_OUTD;
        int o   = rem / D_OUTD;
        g_h[o * D_IN + i] = d;
        g_w[o * D_IN + i] = v;
    }
}

// x [D_IN][N] -> xT [N][D_IN] so sketch blocks read a contiguous 4KB column.
__global__ void xt_kernel(const float* __restrict__ in, float* __restrict__ out) {
    __shared__ float tile[32][33];
    int i0 = blockIdx.x * 32;
    int n0 = blockIdx.y * 32;
    int tx = threadIdx.x;
    int ty = threadIdx.y;
#pragma unroll
    for (int j = 0; j < 32; j += 8)
        tile[ty + j][tx] = in[(i0 + ty + j) * NCOL + n0 + tx];
    __syncthreads();
#pragma unroll
    for (int j = 0; j < 32; j += 8)
        out[(n0 + ty + j) * D_IN + i0 + tx] = tile[tx][ty + j];
}

__device__ __forceinline__ float2 cmul(float2 a, float2 b) {
    return make_float2(a.x * b.x - a.y * b.y, a.x * b.y + a.y * b.x);
}
__device__ __forceinline__ float2 csqr(float2 a) {
    return make_float2(a.x * a.x - a.y * a.y, 2.0f * a.x * a.y);
}
// compile-time 16th roots of unity: e^{-2*pi*i*k/16}, k=0..7
__device__ __forceinline__ float2 c16(int k) {
    constexpr float R[8] = { 1.0f,  0.92387953251128674f,  0.70710678118654757f,  0.38268343236508978f,
                             0.0f, -0.38268343236508978f, -0.70710678118654757f, -0.92387953251128674f };
    constexpr float I[8] = { 0.0f, -0.38268343236508978f, -0.70710678118654757f, -0.92387953251128674f,
                            -1.0f, -0.92387953251128674f, -0.70710678118654757f, -0.38268343236508978f };
    return make_float2(R[k], I[k]);
}

// Full forward 8192-pt DIF on register arrays XR/XI (macro keeps all array
// indices compile-time static -- no scratch). Uses outer scope: wt, bb16, tc,
// bre, bim, t, s, base. Output: spectrum at slot q=base+32j in register j,
// slots hold bit-reversed content.
#define FWD_FFT(XR, XI)                                                          \
    {                                                                            \
        float2 ba = wt;                                                          \
        _Pragma("unroll")                                                        \
        for (int m = 3; m >= 0; --m) {                                           \
            const int half = 1 << m;                                             \
            float2 tw[8];                                                        \
            _Pragma("unroll")                                                    \
            for (int lo = 0; lo < half; ++lo) tw[lo] = cmul(ba, c16(lo << (3 - m))); \
            _Pragma("unroll")                                                    \
            for (int p = 0; p < 8; ++p) {                                        \
                const int lo = p & (half - 1);                                   \
                const int hi = p >> m;                                           \
                const int j0 = (hi << (m + 1)) + lo;                             \
                const int j1 = j0 + half;                                        \
                const float2 w = tw[lo];                                         \
                float ar = XR[j0], ai = XI[j0];                                  \
                float br = XR[j1], bi = XI[j1];                                  \
                XR[j0] = ar + br; XI[j0] = ai + bi;                              \
                float dr = ar - br, di = ai - bi;                                \
                XR[j1] = dr * w.x - di * w.y;                                    \
                XI[j1] = dr * w.y + di * w.x;                                    \
            }                                                                    \
            if (m) ba = csqr(ba);                                                \
        }                                                                        \
    }                                                                            \
    _Pragma("unroll")                                                            \
    for (int j = 0; j < 16; ++j) { bre[t + 512 * j] = XR[j]; bim[t + 512 * j] = XI[j]; } \
    __syncthreads();                                                             \
    _Pragma("unroll")                                                            \
    for (int j = 0; j < 16; ++j) { XR[j] = bre[base + 32 * j]; XI[j] = bim[base + 32 * j]; } \
    __syncthreads();                                                             \
    {                                                                            \
        float2 bb = bb16;                                                        \
        _Pragma("unroll")                                                        \
        for (int m = 3; m >= 0; --m) {                                           \
            const int half = 1 << m;                                             \
            float2 tw[8];                                                        \
            _Pragma("unroll")                                                    \
            for (int lo = 0; lo < half; ++lo) tw[lo] = cmul(bb, c16(lo << (3 - m))); \
            _Pragma("unroll")                                                    \
            for (int p = 0; p < 8; ++p) {                                        \
                const int lo = p & (half - 1);                                   \
                const int hi = p >> m;                                           \
                const int j0 = (hi << (m + 1)) + lo;                             \
                const int j1 = j0 + half;                                        \
                const float2 w = tw[lo];                                         \
                float ar = XR[j0], ai = XI[j0];                                  \
                float br = XR[j1], bi = XI[j1];                                  \
                XR[j0] = ar + br; XI[j0] = ai + bi;                              \
                float dr = ar - br, di = ai - bi;                                \
                XR[j1] = dr * w.x - di * w.y;                                    \
                XI[j1] = dr * w.y + di * w.x;                                    \
            }                                                                    \
            if (m) bb = csqr(bb);                                                \
        }                                                                        \
    }                                                                            \
    _Pragma("unroll")                                                            \
    for (int lh = 4; lh >= 0; --lh) {                                            \
        const int st = 1 << lh;                                                  \
        float2 w = tc[lh];                                                       \
        const bool up = (s & st) != 0;                                           \
        const float sg = up ? -1.0f : 1.0f;                                      \
        if (!up) { w.x = 1.0f; w.y = 0.0f; }                                     \
        _Pragma("unroll")                                                        \
        for (int j = 0; j < 16; ++j) {                                           \
            float pr = __shfl_xor(XR[j], st, 64);                                \
            float pi = __shfl_xor(XI[j], st, 64);                                \
            float tr = pr + sg * XR[j];                                          \
            float ti = pi + sg * XI[j];                                          \
            XR[j] = tr * w.x - ti * w.y;                                         \
            XI[j] = tr * w.y + ti * w.x;                                         \
        }                                                                        \
    }

// 512 threads per column n, 16 complex points per thread, register-resident FFT,
// all twiddles from register squaring chains. Round-5: orders 0 and 1 are packed
// into ONE complex FFT (count sequences are real); F0*F1 is recovered via the
// Hermitian partner, which in bit-reversed storage sits at sigma(q) =
// q ^ (2^floor(log2 q) - 1). FFTs per column: 4 -> 3.
__launch_bounds__(512, 2)
__global__ void sketch_kernel(const float* __restrict__ x, float* __restrict__ outbuf,
                              int staged, int xcoal) {
    __shared__ float bre[D_OUTD];
    __shared__ float bim[D_OUTD];
    const int n = blockIdx.x;
    const int t = threadIdx.x;
    const int s = t & 31;
    const int base = ((t >> 5) << 9) + s;   // 512*b + s

    float xv0, xv1;
    if (xcoal) {
        xv0 = x[n * D_IN + t];
        xv1 = x[n * D_IN + t + 512];
    } else {
        xv0 = x[t * NCOL + n];
        xv1 = x[(t + 512) * NCOL + n];
    }

    // ---- twiddle seeds (coalesced loads) + register chains ----
    const float2 wt  = g_tw[t];        // W^t
    const float2 ws  = g_tw[s];        // W^s
    const float2 w15 = g_tw[s & 15];   // W^(s&15)
    const float2 bb16 = csqr(csqr(csqr(csqr(ws))));           // W^(16s)
    float2 t4 = w15;                                           // -> W^(256*(s&15))
#pragma unroll
    for (int q = 0; q < 8; ++q) t4 = csqr(t4);
    const float sg3 = ((s >> 3) & 1) ? -1.0f : 1.0f;
    const float sg2 = ((s >> 2) & 1) ? -1.0f : 1.0f;
    const float sg1 = ((s >> 1) & 1) ? -1.0f : 1.0f;
    float2 t3 = csqr(t4); t3.x *= sg3; t3.y *= sg3;            // W^(512*(s&7))
    float2 t2 = csqr(t3); t2.x *= sg2; t2.y *= sg2;            // W^(1024*(s&3))
    float2 t1 = csqr(t2); t1.x *= sg1; t1.y *= sg1;            // W^(2048*(s&1))
    const float2 tc[5] = { make_float2(1.0f, 0.0f), t1, t2, t3, t4 };

    float Pre[16], Pim[16];

    // ================= pass 0: orders 0 & 1 packed (Z = c0 + i*c1) =================
    {
        float Xre[16], Xim[16];
#pragma unroll
        for (int j = 0; j < 16; ++j) { bre[t + 512 * j] = 0.0f; bim[t + 512 * j] = 0.0f; }
        __syncthreads();
        {
            atomicAdd(&bre[g_h[t]],              g_w[t]              * xv0);
            atomicAdd(&bre[g_h[t + 512]],        g_w[t + 512]        * xv1);
            atomicAdd(&bim[g_h[D_IN + t]],       g_w[D_IN + t]       * xv0);
            atomicAdd(&bim[g_h[D_IN + t + 512]], g_w[D_IN + t + 512] * xv1);
        }
        __syncthreads();
#pragma unroll
        for (int j = 0; j < 16; ++j) { Xre[j] = bre[t + 512 * j]; Xim[j] = bim[t + 512 * j]; }
        __syncthreads();   // LDS reused inside FWD_FFT

        FWD_FFT(Xre, Xim)

        // ---- Hermitian unpack + product: G = F0*F1 = -i*(A^2 - B^2)/4 ----
        // A = Z[slot q], B = conj(Z[slot sigma(q)])
#pragma unroll
        for (int j = 0; j < 16; ++j) { bre[base + 32 * j] = Xre[j]; bim[base + 32 * j] = Xim[j]; }
        __syncthreads();
#pragma unroll
        for (int j = 0; j < 16; ++j) {
            const int q  = base + 32 * j;
            const int sq = q ? (q ^ ((1 << (31 - __clz(q))) - 1)) : 0;
            const float pbr =  bre[sq];
            const float pbi = -bim[sq];
            const float a2r = Xre[j] * Xre[j] - Xim[j] * Xim[j];
            const float a2i = 2.0f * Xre[j] * Xim[j];
            const float b2r = pbr * pbr - pbi * pbi;
            const float b2i = 2.0f * pbr * pbi;
            const float dr = a2r - b2r, di = a2i - b2i;
            Pre[j] =  0.25f * di;
            Pim[j] = -0.25f * dr;
        }
        __syncthreads();
    }

    // ================= pass 1: order 2 (real input) =================
    {
        float Xre[16], Xim[16];
#pragma unroll
        for (int j = 0; j < 16; ++j) bre[t + 512 * j] = 0.0f;
        __syncthreads();
        {
            atomicAdd(&bre[g_h[2 * D_IN + t]],       g_w[2 * D_IN + t]       * xv0);
            atomicAdd(&bre[g_h[2 * D_IN + t + 512]], g_w[2 * D_IN + t + 512] * xv1);
        }
        __syncthreads();
#pragma unroll
        for (int j = 0; j < 16; ++j) { Xre[j] = bre[t + 512 * j]; Xim[j] = 0.0f; }
        __syncthreads();

        FWD_FFT(Xre, Xim)

        // P = G * F2 (elementwise, same slot layout)
#pragma unroll
        for (int j = 0; j < 16; ++j) {
            float ar = Pre[j], ai = Pim[j];
            Pre[j] = ar * Xre[j] - ai * Xim[j];
            Pim[j] = ar * Xim[j] + ai * Xre[j];
        }
    }

    // ================= inverse DIT =================
    // phase C inverse: lh=0..4, conj(tc[lh])
#pragma unroll
    for (int lh = 0; lh <= 4; ++lh) {
        const int st = 1 << lh;
        float2 w = tc[lh];
        w.y = -w.y;
        const bool up = (s & st) != 0;
        const float sg = up ? -1.0f : 1.0f;
        if (!up) { w.x = 1.0f; w.y = 0.0f; }
#pragma unroll
        for (int j = 0; j < 16; ++j) {
            float er = Pre[j] * w.x - Pim[j] * w.y;
            float ei = Pre[j] * w.y + Pim[j] * w.x;
            float pr = __shfl_xor(er, st, 64);
            float pi = __shfl_xor(ei, st, 64);
            Pre[j] = pr + sg * er;
            Pim[j] = pi + sg * ei;
        }
    }

    // phase B inverse: bases bb128..bb16 (forward values; butterfly conjugates inline)
    {
        const float2 bb32 = csqr(bb16), bb64 = csqr(bb32), bb128 = csqr(bb64);
        const float2 bbs[4] = { bb128, bb64, bb32, bb16 };
#pragma unroll
        for (int m = 0; m <= 3; ++m) {
            const int half = 1 << m;
            float2 tw[8];
#pragma unroll
            for (int lo = 0; lo < half; ++lo) tw[lo] = cmul(bbs[m], c16(lo << (3 - m)));
#pragma unroll
            for (int p = 0; p < 8; ++p) {
                const int lo = p & (half - 1);
                const int hi = p >> m;
                const int j0 = (hi << (m + 1)) + lo;
                const int j1 = j0 + half;
                const float2 w = tw[lo];
                float tr = Pre[j1] * w.x + Pim[j1] * w.y;   // mul by conj(w)
                float ti = Pim[j1] * w.x - Pre[j1] * w.y;
                Pre[j1] = Pre[j0] - tr; Pim[j1] = Pim[j0] - ti;
                Pre[j0] += tr; Pim[j0] += ti;
            }
        }
    }

    // exchange B->A
#pragma unroll
    for (int j = 0; j < 16; ++j) { bre[base + 32 * j] = Pre[j]; bim[base + 32 * j] = Pim[j]; }
    __syncthreads();
#pragma unroll
    for (int j = 0; j < 16; ++j) { Pre[j] = bre[t + 512 * j]; Pim[j] = bim[t + 512 * j]; }

    // phase A inverse: bases wt^8..wt^1
    {
        const float2 ba2 = csqr(wt), ba4 = csqr(ba2), ba8 = csqr(ba4);
        const float2 bas[4] = { ba8, ba4, ba2, wt };
#pragma unroll
        for (int m = 0; m <= 3; ++m) {
            const int half = 1 << m;
            float2 tw[8];
#pragma unroll
            for (int lo = 0; lo < half; ++lo) tw[lo] = cmul(bas[m], c16(lo << (3 - m)));
#pragma unroll
            for (int p = 0; p < 8; ++p) {
                const int lo = p & (half - 1);
                const int hi = p >> m;
                const int j0 = (hi << (m + 1)) + lo;
                const int j1 = j0 + half;
                const float2 w = tw[lo];
                float tr = Pre[j1] * w.x + Pim[j1] * w.y;   // mul by conj(w)
                float ti = Pim[j1] * w.x - Pre[j1] * w.y;
                Pre[j1] = Pre[j0] - tr; Pim[j1] = Pim[j0] - ti;
                Pre[j0] += tr; Pim[j0] += ti;
            }
        }
    }

    const float scale = 1.0f / (float)D_OUTD;
    if (staged) {
#pragma unroll
        for (int j = 0; j < 16; ++j)
            outbuf[n * D_OUTD + t + 512 * j] = Pre[j] * scale;
    } else {
#pragma unroll
        for (int j = 0; j < 16; ++j)
            outbuf[(t + 512 * j) * NCOL + n] = Pre[j] * scale;
    }
}

// [N][D_out] -> [D_out][N], 32x32 tiles
__global__ void transpose_kernel(const float* __restrict__ in, float* __restrict__ out) {
    __shared__ float tile[32][33];
    int d0 = blockIdx.x * 32;
    int n0 = blockIdx.y * 32;
    int tx = threadIdx.x;
    int ty = threadIdx.y;
#pragma unroll
    for (int j = 0; j < 32; j += 8)
        tile[ty + j][tx] = in[(n0 + ty + j) * D_OUTD + d0 + tx];
    __syncthreads();
#pragma unroll
    for (int j = 0; j < 32; j += 8)
        out[(d0 + ty + j) * NCOL + n0 + tx] = tile[tx][ty + j];
}

extern "C" void kernel_launch(void* const* d_in, const int* in_sizes, int n_in,
                              void* d_out, int out_size, void* d_ws, size_t ws_size,
                              hipStream_t stream) {
    (void)in_sizes; (void)n_in; (void)out_size;
    const float* x     = (const float*)d_in[0];
    const float* hmaps = (const float*)d_in[1];
    float* out = (float*)d_out;

    tw_kernel<<<(D_OUTD / 2 + 255) / 256, 256, 0, stream>>>();
    extract_kernel<<<(ORDER * D_OUTD * D_IN + 255) / 256, 256, 0, stream>>>(hmaps);

    const size_t stage_bytes = (size_t)NCOL * D_OUTD * sizeof(float);
    const size_t xt_bytes    = (size_t)NCOL * D_IN * sizeof(float);

    const float* xs = x;
    int xcoal = 0;
    if (ws_size >= stage_bytes + xt_bytes) {
        float* xT = (float*)((char*)d_ws + stage_bytes);
        xt_kernel<<<dim3(D_IN / 32, NCOL / 32), dim3(32, 8), 0, stream>>>(x, xT);
        xs = xT;
        xcoal = 1;
    }

    if (ws_size >= stage_bytes) {
        float* stag = (float*)d_ws;
        sketch_kernel<<<NCOL, 512, 0, stream>>>(xs, stag, 1, xcoal);
        transpose_kernel<<<dim3(D_OUTD / 32, NCOL / 32), dim3(32, 8), 0, stream>>>(stag, out);
    } else {
        sketch_kernel<<<NCOL, 512, 0, stream>>>(xs, out, 0, xcoal);
    }
}

// Round 6
// 198.355 us; speedup vs baseline: 3.3064x; 1.1647x over previous
//
#include <hip/hip_runtime.h>

#define D_IN   1024
#define D_OUTD 8192
#define ORDER  3
#define NCOL   2048

// Persistent device-side tables (rewritten every kernel_launch call).
__device__ float2 g_tw[D_OUTD / 2];      // W_8192^k, k in [0,4096)
__device__ int    g_h[ORDER * D_IN];
__device__ float  g_w[ORDER * D_IN];

__global__ void tw_kernel() {
    int k = blockIdx.x * 256 + threadIdx.x;
    if (k < D_OUTD / 2) {
        double ang = -2.0 * 3.14159265358979323846 * (double)k / (double)D_OUTD;
        g_tw[k] = make_float2((float)cos(ang), (float)sin(ang));
    }
}

__global__ void extract_kernel(const float* __restrict__ hmaps) {
    int idx = blockIdx.x * 256 + threadIdx.x;
    if (idx >= ORDER * D_OUTD * D_IN) return;
    float v = hmaps[idx];
    if (v != 0.0f) {
        int i   = idx % D_IN;
        int rem = idx / D_IN;
        int d   = rem % D_OUTD;
        int o   = rem / D_OUTD;
        g_h[o * D_IN + i] = d;
        g_w[o * D_IN + i] = v;
    }
}

// x [D_IN][N] -> xT [N][D_IN] so sketch blocks read a contiguous 4KB column.
__global__ void xt_kernel(const float* __restrict__ in, float* __restrict__ out) {
    __shared__ float tile[32][33];
    int i0 = blockIdx.x * 32;
    int n0 = blockIdx.y * 32;
    int tx = threadIdx.x;
    int ty = threadIdx.y;
#pragma unroll
    for (int j = 0; j < 32; j += 8)
        tile[ty + j][tx] = in[(i0 + ty + j) * NCOL + n0 + tx];
    __syncthreads();
#pragma unroll
    for (int j = 0; j < 32; j += 8)
        out[(n0 + ty + j) * D_IN + i0 + tx] = tile[tx][ty + j];
}

__device__ __forceinline__ float2 cmul(float2 a, float2 b) {
    return make_float2(a.x * b.x - a.y * b.y, a.x * b.y + a.y * b.x);
}
__device__ __forceinline__ float2 csqr(float2 a) {
    return make_float2(a.x * a.x - a.y * a.y, 2.0f * a.x * a.y);
}
// compile-time 16th roots of unity: e^{-2*pi*i*k/16}, k=0..7
__device__ __forceinline__ float2 c16(int k) {
    constexpr float R[8] = { 1.0f,  0.92387953251128674f,  0.70710678118654757f,  0.38268343236508978f,
                             0.0f, -0.38268343236508978f, -0.70710678118654757f, -0.92387953251128674f };
    constexpr float I[8] = { 0.0f, -0.38268343236508978f, -0.70710678118654757f, -0.92387953251128674f,
                            -1.0f, -0.92387953251128674f, -0.70710678118654757f, -0.38268343236508978f };
    return make_float2(R[k], I[k]);
}

// Full forward 8192-pt DIF on register arrays XR/XI (macro keeps all array
// indices compile-time static -- no scratch). Uses outer scope: wt, bb16, tc,
// bre, bim, t, s, base. Output: spectrum at slot q=base+32j in register j,
// slots hold bit-reversed content.
#define FWD_FFT(XR, XI)                                                          \
    {                                                                            \
        float2 ba = wt;                                                          \
        _Pragma("unroll")                                                        \
        for (int m = 3; m >= 0; --m) {                                           \
            const int half = 1 << m;                                             \
            float2 tw[8];                                                        \
            _Pragma("unroll")                                                    \
            for (int lo = 0; lo < half; ++lo) tw[lo] = cmul(ba, c16(lo << (3 - m))); \
            _Pragma("unroll")                                                    \
            for (int p = 0; p < 8; ++p) {                                        \
                const int lo = p & (half - 1);                                   \
                const int hi = p >> m;                                           \
                const int j0 = (hi << (m + 1)) + lo;                             \
                const int j1 = j0 + half;                                        \
                const float2 w = tw[lo];                                         \
                float ar = XR[j0], ai = XI[j0];                                  \
                float br = XR[j1], bi = XI[j1];                                  \
                XR[j0] = ar + br; XI[j0] = ai + bi;                              \
                float dr = ar - br, di = ai - bi;                                \
                XR[j1] = dr * w.x - di * w.y;                                    \
                XI[j1] = dr * w.y + di * w.x;                                    \
            }                                                                    \
            if (m) ba = csqr(ba);                                                \
        }                                                                        \
    }                                                                            \
    _Pragma("unroll")                                                            \
    for (int j = 0; j < 16; ++j) { bre[t + 512 * j] = XR[j]; bim[t + 512 * j] = XI[j]; } \
    __syncthreads();                                                             \
    _Pragma("unroll")                                                            \
    for (int j = 0; j < 16; ++j) { XR[j] = bre[base + 32 * j]; XI[j] = bim[base + 32 * j]; } \
    __syncthreads();                                                             \
    {                                                                            \
        float2 bb = bb16;                                                        \
        _Pragma("unroll")                                                        \
        for (int m = 3; m >= 0; --m) {                                           \
            const int half = 1 << m;                                             \
            float2 tw[8];                                                        \
            _Pragma("unroll")                                                    \
            for (int lo = 0; lo < half; ++lo) tw[lo] = cmul(bb, c16(lo << (3 - m))); \
            _Pragma("unroll")                                                    \
            for (int p = 0; p < 8; ++p) {                                        \
                const int lo = p & (half - 1);                                   \
                const int hi = p >> m;                                           \
                const int j0 = (hi << (m + 1)) + lo;                             \
                const int j1 = j0 + half;                                        \
                const float2 w = tw[lo];                                         \
                float ar = XR[j0], ai = XI[j0];                                  \
                float br = XR[j1], bi = XI[j1];                                  \
                XR[j0] = ar + br; XI[j0] = ai + bi;                              \
                float dr = ar - br, di = ai - bi;                                \
                XR[j1] = dr * w.x - di * w.y;                                    \
                XI[j1] = dr * w.y + di * w.x;                                    \
            }                                                                    \
            if (m) bb = csqr(bb);                                                \
        }                                                                        \
    }                                                                            \
    _Pragma("unroll")                                                            \
    for (int lh = 4; lh >= 0; --lh) {                                            \
        const int st = 1 << lh;                                                  \
        float2 w = tc[lh];                                                       \
        const bool up = (s & st) != 0;                                           \
        const float sg = up ? -1.0f : 1.0f;                                      \
        if (!up) { w.x = 1.0f; w.y = 0.0f; }                                     \
        _Pragma("unroll")                                                        \
        for (int j = 0; j < 16; ++j) {                                           \
            float pr = __shfl_xor(XR[j], st, 64);                                \
            float pi = __shfl_xor(XI[j], st, 64);                                \
            float tr = pr + sg * XR[j];                                          \
            float ti = pi + sg * XI[j];                                          \
            XR[j] = tr * w.x - ti * w.y;                                         \
            XI[j] = tr * w.y + ti * w.x;                                         \
        }                                                                        \
    }

// Round-6: each block handles TWO columns (n0, n1). Hermitian packing is used
// three ways: FFT-A = c2[n0] + i*c2[n1] (split -> F2 for both columns);
// FFT-B/C = c0 + i*c1 per column (product via partner); ONE inverse of
// P0 + i*P1 yields both real outputs (Re -> n0, Im -> n1).
// FFT bodies per 2 columns: 6 -> 4. Partner slot in bit-reversed storage:
// sigma(q) = q ^ (2^floor(log2 q) - 1), sigma(0)=0.
__launch_bounds__(512, 2)
__global__ void sketch_kernel(const float* __restrict__ x, float* __restrict__ outbuf,
                              int staged, int xcoal) {
    __shared__ float bre[D_OUTD];
    __shared__ float bim[D_OUTD];
    const int n0 = 2 * blockIdx.x;
    const int n1 = n0 + 1;
    const int t = threadIdx.x;
    const int s = t & 31;
    const int base = ((t >> 5) << 9) + s;   // 512*b + s

    float xA0, xA1, xB0, xB1;
    if (xcoal) {
        xA0 = x[n0 * D_IN + t]; xA1 = x[n0 * D_IN + t + 512];
        xB0 = x[n1 * D_IN + t]; xB1 = x[n1 * D_IN + t + 512];
    } else {
        xA0 = x[t * NCOL + n0]; xA1 = x[(t + 512) * NCOL + n0];
        xB0 = x[t * NCOL + n1]; xB1 = x[(t + 512) * NCOL + n1];
    }

    // ---- twiddle seeds (coalesced loads) + register chains ----
    const float2 wt  = g_tw[t];        // W^t
    const float2 ws  = g_tw[s];        // W^s
    const float2 w15 = g_tw[s & 15];   // W^(s&15)
    const float2 bb16 = csqr(csqr(csqr(csqr(ws))));           // W^(16s)
    float2 t4 = w15;                                           // -> W^(256*(s&15))
#pragma unroll
    for (int q = 0; q < 8; ++q) t4 = csqr(t4);
    const float sg3 = ((s >> 3) & 1) ? -1.0f : 1.0f;
    const float sg2 = ((s >> 2) & 1) ? -1.0f : 1.0f;
    const float sg1 = ((s >> 1) & 1) ? -1.0f : 1.0f;
    float2 t3 = csqr(t4); t3.x *= sg3; t3.y *= sg3;            // W^(512*(s&7))
    float2 t2 = csqr(t3); t2.x *= sg2; t2.y *= sg2;            // W^(1024*(s&3))
    float2 t1 = csqr(t2); t1.x *= sg1; t1.y *= sg1;            // W^(2048*(s&1))
    const float2 tc[5] = { make_float2(1.0f, 0.0f), t1, t2, t3, t4 };

    float P0r[16], P0i[16];   // F2[n0] -> P0
    float P1r[16], P1i[16];   // F2[n1] -> P1

    // ================= FFT-A: Z = c2[n0] + i*c2[n1] =================
    {
        float Ar[16], Ai[16];
#pragma unroll
        for (int j = 0; j < 16; ++j) { bre[t + 512 * j] = 0.0f; bim[t + 512 * j] = 0.0f; }
        __syncthreads();
        {
            const int   h2a = g_h[2 * D_IN + t];
            const float w2a = g_w[2 * D_IN + t];
            const int   h2b = g_h[2 * D_IN + t + 512];
            const float w2b = g_w[2 * D_IN + t + 512];
            atomicAdd(&bre[h2a], w2a * xA0);
            atomicAdd(&bre[h2b], w2b * xA1);
            atomicAdd(&bim[h2a], w2a * xB0);
            atomicAdd(&bim[h2b], w2b * xB1);
        }
        __syncthreads();
#pragma unroll
        for (int j = 0; j < 16; ++j) { Ar[j] = bre[t + 512 * j]; Ai[j] = bim[t + 512 * j]; }
        __syncthreads();

        FWD_FFT(Ar, Ai)

        // Hermitian split: F2_n0 = (A+B)/2, F2_n1 = (A-B)/(2i), B = conj(Z[sigma(q)])
#pragma unroll
        for (int j = 0; j < 16; ++j) { bre[base + 32 * j] = Ar[j]; bim[base + 32 * j] = Ai[j]; }
        __syncthreads();
#pragma unroll
        for (int j = 0; j < 16; ++j) {
            const int q  = base + 32 * j;
            const int sq = q ? (q ^ ((1 << (31 - __clz(q))) - 1)) : 0;
            const float pbr =  bre[sq];
            const float pbi = -bim[sq];
            P0r[j] =  0.5f * (Ar[j] + pbr);
            P0i[j] =  0.5f * (Ai[j] + pbi);
            P1r[j] =  0.5f * (Ai[j] - pbi);
            P1i[j] = -0.5f * (Ar[j] - pbr);
        }
        __syncthreads();
    }

    // ================= FFT-B: Z = c0[n0] + i*c1[n0]; P0 = G0 * F2_n0 =================
    {
        float Ar[16], Ai[16];
#pragma unroll
        for (int j = 0; j < 16; ++j) { bre[t + 512 * j] = 0.0f; bim[t + 512 * j] = 0.0f; }
        __syncthreads();
        {
            atomicAdd(&bre[g_h[t]],              g_w[t]              * xA0);
            atomicAdd(&bre[g_h[t + 512]],        g_w[t + 512]        * xA1);
            atomicAdd(&bim[g_h[D_IN + t]],       g_w[D_IN + t]       * xA0);
            atomicAdd(&bim[g_h[D_IN + t + 512]], g_w[D_IN + t + 512] * xA1);
        }
        __syncthreads();
#pragma unroll
        for (int j = 0; j < 16; ++j) { Ar[j] = bre[t + 512 * j]; Ai[j] = bim[t + 512 * j]; }
        __syncthreads();

        FWD_FFT(Ar, Ai)

#pragma unroll
        for (int j = 0; j < 16; ++j) { bre[base + 32 * j] = Ar[j]; bim[base + 32 * j] = Ai[j]; }
        __syncthreads();
#pragma unroll
        for (int j = 0; j < 16; ++j) {
            const int q  = base + 32 * j;
            const int sq = q ? (q ^ ((1 << (31 - __clz(q))) - 1)) : 0;
            const float pbr =  bre[sq];
            const float pbi = -bim[sq];
            const float a2r = Ar[j] * Ar[j] - Ai[j] * Ai[j];
            const float a2i = 2.0f * Ar[j] * Ai[j];
            const float b2r = pbr * pbr - pbi * pbi;
            const float b2i = 2.0f * pbr * pbi;
            const float gr =  0.25f * (a2i - b2i);   // G = -i*(A^2 - B^2)/4
            const float gi = -0.25f * (a2r - b2r);
            const float fr = P0r[j], fi = P0i[j];
            P0r[j] = gr * fr - gi * fi;
            P0i[j] = gr * fi + gi * fr;
        }
        __syncthreads();
    }

    // ================= FFT-C: Z = c0[n1] + i*c1[n1]; P1 = G1 * F2_n1 =================
    {
        float Ar[16], Ai[16];
#pragma unroll
        for (int j = 0; j < 16; ++j) { bre[t + 512 * j] = 0.0f; bim[t + 512 * j] = 0.0f; }
        __syncthreads();
        {
            atomicAdd(&bre[g_h[t]],              g_w[t]              * xB0);
            atomicAdd(&bre[g_h[t + 512]],        g_w[t + 512]        * xB1);
            atomicAdd(&bim[g_h[D_IN + t]],       g_w[D_IN + t]       * xB0);
            atomicAdd(&bim[g_h[D_IN + t + 512]], g_w[D_IN + t + 512] * xB1);
        }
        __syncthreads();
#pragma unroll
        for (int j = 0; j < 16; ++j) { Ar[j] = bre[t + 512 * j]; Ai[j] = bim[t + 512 * j]; }
        __syncthreads();

        FWD_FFT(Ar, Ai)

#pragma unroll
        for (int j = 0; j < 16; ++j) { bre[base + 32 * j] = Ar[j]; bim[base + 32 * j] = Ai[j]; }
        __syncthreads();
#pragma unroll
        for (int j = 0; j < 16; ++j) {
            const int q  = base + 32 * j;
            const int sq = q ? (q ^ ((1 << (31 - __clz(q))) - 1)) : 0;
            const float pbr =  bre[sq];
            const float pbi = -bim[sq];
            const float a2r = Ar[j] * Ar[j] - Ai[j] * Ai[j];
            const float a2i = 2.0f * Ar[j] * Ai[j];
            const float b2r = pbr * pbr - pbi * pbi;
            const float b2i = 2.0f * pbr * pbi;
            const float gr =  0.25f * (a2i - b2i);
            const float gi = -0.25f * (a2r - b2r);
            const float fr = P1r[j], fi = P1i[j];
            P1r[j] = gr * fr - gi * fi;
            P1i[j] = gr * fi + gi * fr;
        }
        __syncthreads();
    }

    // ================= pack Q = P0 + i*P1, then ONE inverse DIT =================
    float Qr[16], Qi[16];
#pragma unroll
    for (int j = 0; j < 16; ++j) {
        Qr[j] = P0r[j] - P1i[j];
        Qi[j] = P0i[j] + P1r[j];
    }

    // phase C inverse: lh=0..4, conj(tc[lh])
#pragma unroll
    for (int lh = 0; lh <= 4; ++lh) {
        const int st = 1 << lh;
        float2 w = tc[lh];
        w.y = -w.y;
        const bool up = (s & st) != 0;
        const float sg = up ? -1.0f : 1.0f;
        if (!up) { w.x = 1.0f; w.y = 0.0f; }
#pragma unroll
        for (int j = 0; j < 16; ++j) {
            float er = Qr[j] * w.x - Qi[j] * w.y;
            float ei = Qr[j] * w.y + Qi[j] * w.x;
            float pr = __shfl_xor(er, st, 64);
            float pi = __shfl_xor(ei, st, 64);
            Qr[j] = pr + sg * er;
            Qi[j] = pi + sg * ei;
        }
    }

    // phase B inverse: bases bb128..bb16 (butterfly conjugates inline)
    {
        const float2 bb32 = csqr(bb16), bb64 = csqr(bb32), bb128 = csqr(bb64);
        const float2 bbs[4] = { bb128, bb64, bb32, bb16 };
#pragma unroll
        for (int m = 0; m <= 3; ++m) {
            const int half = 1 << m;
            float2 tw[8];
#pragma unroll
            for (int lo = 0; lo < half; ++lo) tw[lo] = cmul(bbs[m], c16(lo << (3 - m)));
#pragma unroll
            for (int p = 0; p < 8; ++p) {
                const int lo = p & (half - 1);
                const int hi = p >> m;
                const int j0 = (hi << (m + 1)) + lo;
                const int j1 = j0 + half;
                const float2 w = tw[lo];
                float tr = Qr[j1] * w.x + Qi[j1] * w.y;   // mul by conj(w)
                float ti = Qi[j1] * w.x - Qr[j1] * w.y;
                Qr[j1] = Qr[j0] - tr; Qi[j1] = Qi[j0] - ti;
                Qr[j0] += tr; Qi[j0] += ti;
            }
        }
    }

    // exchange B->A
#pragma unroll
    for (int j = 0; j < 16; ++j) { bre[base + 32 * j] = Qr[j]; bim[base + 32 * j] = Qi[j]; }
    __syncthreads();
#pragma unroll
    for (int j = 0; j < 16; ++j) { Qr[j] = bre[t + 512 * j]; Qi[j] = bim[t + 512 * j]; }

    // phase A inverse: bases wt^8..wt^1
    {
        const float2 ba2 = csqr(wt), ba4 = csqr(ba2), ba8 = csqr(ba4);
        const float2 bas[4] = { ba8, ba4, ba2, wt };
#pragma unroll
        for (int m = 0; m <= 3; ++m) {
            const int half = 1 << m;
            float2 tw[8];
#pragma unroll
            for (int lo = 0; lo < half; ++lo) tw[lo] = cmul(bas[m], c16(lo << (3 - m)));
#pragma unroll
            for (int p = 0; p < 8; ++p) {
                const int lo = p & (half - 1);
                const int hi = p >> m;
                const int j0 = (hi << (m + 1)) + lo;
                const int j1 = j0 + half;
                const float2 w = tw[lo];
                float tr = Qr[j1] * w.x + Qi[j1] * w.y;   // mul by conj(w)
                float ti = Qi[j1] * w.x - Qr[j1] * w.y;
                Qr[j1] = Qr[j0] - tr; Qi[j1] = Qi[j0] - ti;
                Qr[j0] += tr; Qi[j0] += ti;
            }
        }
    }

    const float scale = 1.0f / (float)D_OUTD;
    if (staged) {
#pragma unroll
        for (int j = 0; j < 16; ++j) {
            outbuf[n0 * D_OUTD + t + 512 * j] = Qr[j] * scale;   // Re -> column n0
            outbuf[n1 * D_OUTD + t + 512 * j] = Qi[j] * scale;   // Im -> column n1
        }
    } else {
#pragma unroll
        for (int j = 0; j < 16; ++j) {
            outbuf[(t + 512 * j) * NCOL + n0] = Qr[j] * scale;
            outbuf[(t + 512 * j) * NCOL + n1] = Qi[j] * scale;
        }
    }
}

// [N][D_out] -> [D_out][N], 32x32 tiles
__global__ void transpose_kernel(const float* __restrict__ in, float* __restrict__ out) {
    __shared__ float tile[32][33];
    int d0 = blockIdx.x * 32;
    int n0 = blockIdx.y * 32;
    int tx = threadIdx.x;
    int ty = threadIdx.y;
#pragma unroll
    for (int j = 0; j < 32; j += 8)
        tile[ty + j][tx] = in[(n0 + ty + j) * D_OUTD + d0 + tx];
    __syncthreads();
#pragma unroll
    for (int j = 0; j < 32; j += 8)
        out[(d0 + ty + j) * NCOL + n0 + tx] = tile[tx][ty + j];
}

extern "C" void kernel_launch(void* const* d_in, const int* in_sizes, int n_in,
                              void* d_out, int out_size, void* d_ws, size_t ws_size,
                              hipStream_t stream) {
    (void)in_sizes; (void)n_in; (void)out_size;
    const float* x     = (const float*)d_in[0];
    const float* hmaps = (const float*)d_in[1];
    float* out = (float*)d_out;

    tw_kernel<<<(D_OUTD / 2 + 255) / 256, 256, 0, stream>>>();
    extract_kernel<<<(ORDER * D_OUTD * D_IN + 255) / 256, 256, 0, stream>>>(hmaps);

    const size_t stage_bytes = (size_t)NCOL * D_OUTD * sizeof(float);
    const size_t xt_bytes    = (size_t)NCOL * D_IN * sizeof(float);

    const float* xs = x;
    int xcoal = 0;
    if (ws_size >= stage_bytes + xt_bytes) {
        float* xT = (float*)((char*)d_ws + stage_bytes);
        xt_kernel<<<dim3(D_IN / 32, NCOL / 32), dim3(32, 8), 0, stream>>>(x, xT);
        xs = xT;
        xcoal = 1;
    }

    if (ws_size >= stage_bytes) {
        float* stag = (float*)d_ws;
        sketch_kernel<<<NCOL / 2, 512, 0, stream>>>(xs, stag, 1, xcoal);
        transpose_kernel<<<dim3(D_OUTD / 32, NCOL / 32), dim3(32, 8), 0, stream>>>(stag, out);
    } else {
        sketch_kernel<<<NCOL / 2, 512, 0, stream>>>(xs, out, 0, xcoal);
    }
}